// Round 3
// baseline (8519.312 us; speedup 1.0000x reference)
//
#include <hip/hip_runtime.h>
#include <math.h>

typedef _Float16 half_t;
typedef _Float16 half8 __attribute__((ext_vector_type(8)));
typedef float floatx16 __attribute__((ext_vector_type(16)));

#define HD 512
#define BB 512
#define TT 336
#define HOR 48
#define MFMA16(a,b,c) __builtin_amdgcn_mfma_f32_32x32x16_f16(a, b, c, 0, 0, 0)

__device__ __forceinline__ float sig_(float x) { return 1.0f / (1.0f + __expf(-x)); }

// ---------------------------------------------------------------------------
// Weight prep -> fp16 frag-linear B layout for mfma_f32_32x32x16_f16.
// B'[jt*NG+g][kc][lane][8]: element = W[row][k], row = g*512 + jt*32 + (lane&31),
// k = kc*16 + (lane>>5)*8 + i.  K-concat: k<512 -> W1, else W2[k-512].
// ---------------------------------------------------------------------------
__global__ __launch_bounds__(256)
void prep_w2(const float* __restrict__ W1, const float* __restrict__ W2,
             half_t* __restrict__ D, int NKC, int NG)
{
    const int t = blockIdx.x * 256 + threadIdx.x;
    if (t >= 16 * NG * NKC * 64) return;
    const int lane = t & 63;
    const int kc = (t >> 6) % NKC;
    const int jtg = (t >> 6) / NKC;
    const int g = jtg % NG, jt = jtg / NG;
    const int row = g * 512 + jt * 32 + (lane & 31);
    const int k = kc * 16 + (lane >> 5) * 8;
    const float* Wp = (k < 512) ? W1 : W2;
    const int kk = (k < 512) ? k : (k - 512);
    const float4 lo = *(const float4*)(Wp + (size_t)row * 512 + kk);
    const float4 hi = *(const float4*)(Wp + (size_t)row * 512 + kk + 4);
    half8 h;
    h[0] = (half_t)lo.x; h[1] = (half_t)lo.y; h[2] = (half_t)lo.z; h[3] = (half_t)lo.w;
    h[4] = (half_t)hi.x; h[5] = (half_t)hi.y; h[6] = (half_t)hi.z; h[7] = (half_t)hi.w;
    *(half8*)(D + (size_t)t * 8) = h;
}

// 32 K-chunks (512 K) of 3-gate MFMA accumulation, frag-direct from global.
__device__ __forceinline__ void kloop32(const half_t* __restrict__ Arow,
                                        const half_t* __restrict__ Bb,
                                        size_t gstride,
                                        floatx16& a0, floatx16& a1, floatx16& a2)
{
    #pragma unroll 8
    for (int kc = 0; kc < 32; ++kc) {
        const half8 a  = *(const half8*)(Arow + kc * 16);
        const half8 w0 = *(const half8*)(Bb + (size_t)kc * 512);
        const half8 w1 = *(const half8*)(Bb + (size_t)kc * 512 + gstride);
        const half8 w2 = *(const half8*)(Bb + (size_t)kc * 512 + 2 * gstride);
        a0 = MFMA16(a, w0, a0);
        a1 = MFMA16(a, w1, a1);
        a2 = MFMA16(a, w2, a2);
    }
}

// ---------------------------------------------------------------------------
// Fused encoder superstep: layer = blockIdx.z + lsel.
// layer0: h0(s) from h0(s-1);  layer1: h1(s-1) from [h0(s-1); h1(s-2)], K=1024.
// Block: 128 thr = 2 waves; wave owns 32 rows x 96 gate-cols, full K. No LDS.
// ---------------------------------------------------------------------------
__global__ __launch_bounds__(128)
void enc_step(const half_t* __restrict__ h0a, const half_t* __restrict__ h1a,
              const half_t* __restrict__ BL0, const half_t* __restrict__ BL1,
              const float* __restrict__ h0pf, const float* __restrict__ h1pf,
              float* __restrict__ h0of, half_t* __restrict__ h0o16,
              float* __restrict__ h1of, half_t* __restrict__ h1o16,
              const float* __restrict__ bih0, const float* __restrict__ bhh0,
              const float* __restrict__ bih1, const float* __restrict__ bhh1,
              const float* __restrict__ Wih0, const float* __restrict__ src,
              int s, int lsel)
{
    const int layer = blockIdx.z + lsel;
    const int jt = blockIdx.x, bt = blockIdx.y;
    const int lane = threadIdx.x & 63, wv = threadIdx.x >> 6;
    const int jl = lane & 31, hi = lane >> 5;
    const int row0 = bt * 64 + wv * 32 + jl;

    floatx16 ar = {}, az = {}, an = {}, ah = {};

    if (layer == 0) {
        const half_t* Arow = h0a + (size_t)row0 * 512 + hi * 8;
        const half_t* Bb   = BL0 + ((size_t)(jt * 3) * 32 * 64 + lane) * 8;
        kloop32(Arow, Bb, (size_t)32 * 512, ar, az, ah);
    } else {
        const half_t* A0 = h0a + (size_t)row0 * 512 + hi * 8;
        const half_t* A1 = h1a + (size_t)row0 * 512 + hi * 8;
        const half_t* B0 = BL1 + ((size_t)(jt * 3) * 64 * 64 + lane) * 8;
        const half_t* B1 = BL1 + (((size_t)(jt * 3) * 64 + 32) * 64 + lane) * 8;
        kloop32(A0, B0, (size_t)64 * 512, ar, az, an);   // i_r,i_z,i_n parts
        kloop32(A1, B1, (size_t)64 * 512, ar, az, ah);   // h_r,h_z,h_n parts
    }

    const int j = jt * 32 + jl;
    const float* bi = layer ? bih1 : bih0;
    const float* bh = layer ? bhh1 : bhh0;
    const float bir = bi[j] + bh[j];
    const float biz = bi[512 + j] + bh[512 + j];
    const float bin = bi[1024 + j];
    const float bhn = bh[1024 + j];
    const float* hpf = layer ? h1pf : h0pf;
    float* hof = layer ? h1of : h0of;
    half_t* ho16 = layer ? h1o16 : h0o16;

    float wr0[8], wz0[8], wn0[8];
    if (layer == 0) {
        #pragma unroll
        for (int i = 0; i < 8; ++i) {
            wr0[i] = Wih0[(size_t)j * 8 + i];
            wz0[i] = Wih0[(size_t)(512 + j) * 8 + i];
            wn0[i] = Wih0[(size_t)(1024 + j) * 8 + i];
        }
    }

    #pragma unroll
    for (int rg = 0; rg < 16; ++rg) {
        const int b = bt * 64 + wv * 32 + (rg & 3) + 4 * hi + 8 * (rg >> 2);
        float gr = ar[rg] + bir;
        float gz = az[rg] + biz;
        float gin = bin;
        const float ghn = ah[rg] + bhn;
        if (layer == 0) {
            const float* sp = src + ((size_t)b * TT + s) * 8;
            #pragma unroll
            for (int i = 0; i < 8; ++i) {
                const float xi = sp[i];
                gr  = fmaf(xi, wr0[i], gr);
                gz  = fmaf(xi, wz0[i], gz);
                gin = fmaf(xi, wn0[i], gin);
            }
        } else {
            gin += an[rg];
        }
        const float r = sig_(gr);
        const float z = sig_(gz);
        const float n = tanhf(gin + r * ghn);
        const float h = (1.f - z) * n + z * hpf[(size_t)b * 512 + j];
        hof[(size_t)b * 512 + j] = h;
        ho16[(size_t)b * 512 + j] = (half_t)h;
    }
}

// ---------------------------------------------------------------------------
// Fused decoder cell + prediction (atomic partial dot into lv[s+1] and out).
// ---------------------------------------------------------------------------
__global__ __launch_bounds__(128)
void dec_step(const half_t* __restrict__ ha, const half_t* __restrict__ Bd,
              const float* __restrict__ hpf, float* __restrict__ hof,
              half_t* __restrict__ ho16,
              const float* __restrict__ cWih, const float* __restrict__ cbih,
              const float* __restrict__ cbhh, const float* __restrict__ tff,
              const float* __restrict__ fcW, const float* __restrict__ fcb,
              const float* __restrict__ lvin, float* __restrict__ lvout,
              float* __restrict__ outp, int s)
{
    const int jt = blockIdx.x, bt = blockIdx.y;
    const int lane = threadIdx.x & 63, wv = threadIdx.x >> 6;
    const int jl = lane & 31, hi = lane >> 5;
    const int row0 = bt * 64 + wv * 32 + jl;

    floatx16 ar = {}, az = {}, ah = {};
    kloop32(ha + (size_t)row0 * 512 + hi * 8,
            Bd + ((size_t)(jt * 3) * 32 * 64 + lane) * 8,
            (size_t)32 * 512, ar, az, ah);

    const int j = jt * 32 + jl;
    float wR[9], wZ[9], wN[9];
    #pragma unroll
    for (int i = 0; i < 9; ++i) {
        wR[i] = cWih[(size_t)j * 9 + i];
        wZ[i] = cWih[(size_t)(512 + j) * 9 + i];
        wN[i] = cWih[(size_t)(1024 + j) * 9 + i];
    }
    const float bir = cbih[j] + cbhh[j];
    const float biz = cbih[512 + j] + cbhh[512 + j];
    const float bin = cbih[1024 + j];
    const float bhn = cbhh[1024 + j];
    const float fw = fcW[j], f0 = fcb[0];

    #pragma unroll
    for (int rg = 0; rg < 16; ++rg) {
        const int b = bt * 64 + wv * 32 + (rg & 3) + 4 * hi + 8 * (rg >> 2);
        const float x0 = lvin[b] + f0;
        const float* sp = tff + ((size_t)b * HOR + s) * 8;
        float gr = ar[rg] + bir + x0 * wR[0];
        float gz = az[rg] + biz + x0 * wZ[0];
        float gin = bin + x0 * wN[0];
        #pragma unroll
        for (int i = 0; i < 8; ++i) {
            const float xi = sp[i];
            gr  = fmaf(xi, wR[1 + i], gr);
            gz  = fmaf(xi, wZ[1 + i], gz);
            gin = fmaf(xi, wN[1 + i], gin);
        }
        const float r = sig_(gr);
        const float z = sig_(gz);
        const float n = tanhf(gin + r * (ah[rg] + bhn));
        const float h = (1.f - z) * n + z * hpf[(size_t)b * 512 + j];
        hof[(size_t)b * 512 + j] = h;
        ho16[(size_t)b * 512 + j] = (half_t)h;

        float v = h * fw;
        #pragma unroll
        for (int off = 16; off > 0; off >>= 1) v += __shfl_xor(v, off);
        if (jl == 0) {
            atomicAdd(lvout + b, v);
            atomicAdd(outp + (size_t)b * HOR + s, v + (jt == 0 ? f0 : 0.f));
        }
    }
}

// ---------------------------------------------------------------------------
// Decoder init: hidden = h1_final @ dec0W^T + dec0b  (no gates)
// ---------------------------------------------------------------------------
__global__ __launch_bounds__(128)
void lin_step(const half_t* __restrict__ ha, const half_t* __restrict__ Bl,
              const float* __restrict__ bias, float* __restrict__ hof,
              half_t* __restrict__ ho16)
{
    const int jt = blockIdx.x, bt = blockIdx.y;
    const int lane = threadIdx.x & 63, wv = threadIdx.x >> 6;
    const int jl = lane & 31, hi = lane >> 5;
    const int row0 = bt * 64 + wv * 32 + jl;
    const half_t* Arow = ha + (size_t)row0 * 512 + hi * 8;
    const half_t* Bb = Bl + ((size_t)jt * 32 * 64 + lane) * 8;
    floatx16 acc = {};
    #pragma unroll 8
    for (int kc = 0; kc < 32; ++kc) {
        const half8 a = *(const half8*)(Arow + kc * 16);
        const half8 w = *(const half8*)(Bb + (size_t)kc * 512);
        acc = MFMA16(a, w, acc);
    }
    const int j = jt * 32 + jl;
    const float bj = bias[j];
    #pragma unroll
    for (int rg = 0; rg < 16; ++rg) {
        const int b = bt * 64 + wv * 32 + (rg & 3) + 4 * hi + 8 * (rg >> 2);
        const float h = acc[rg] + bj;
        hof[(size_t)b * 512 + j] = h;
        ho16[(size_t)b * 512 + j] = (half_t)h;
    }
}

__global__ void lv_init_kernel(const float* __restrict__ src,
                               const float* __restrict__ fcb,
                               float* __restrict__ lvarr)
{
    const int b = threadIdx.x + blockIdx.x * blockDim.x;
    if (b < BB) lvarr[b] = src[((size_t)b * TT + (TT - 1)) * 8] - fcb[0];
}

// ---------------------------------------------------------------------------
extern "C" void kernel_launch(void* const* d_in, const int* in_sizes, int n_in,
                              void* d_out, int out_size, void* d_ws, size_t ws_size,
                              hipStream_t stream)
{
    const float* src   = (const float*)d_in[0];
    const float* tff   = (const float*)d_in[1];
    const float* Wih0  = (const float*)d_in[2];
    const float* Whh0  = (const float*)d_in[3];
    const float* bih0  = (const float*)d_in[4];
    const float* bhh0  = (const float*)d_in[5];
    const float* Wih1  = (const float*)d_in[6];
    const float* Whh1  = (const float*)d_in[7];
    const float* bih1  = (const float*)d_in[8];
    const float* bhh1  = (const float*)d_in[9];
    const float* dec0W = (const float*)d_in[10];
    const float* dec0b = (const float*)d_in[11];
    const float* cWih  = (const float*)d_in[12];
    const float* cWhh  = (const float*)d_in[13];
    const float* cbih  = (const float*)d_in[14];
    const float* cbhh  = (const float*)d_in[15];
    const float* fcW   = (const float*)d_in[16];
    const float* fcb   = (const float*)d_in[17];
    float* out = (float*)d_out;
    float* ws  = (float*)d_ws;

    constexpr size_t N1 = (size_t)BB * HD;    // 262144 floats
    constexpr size_t NHalf = N1 / 2;          // fp16 buffer in float slots

    // --- zero region (single memset) ---
    float*  h0f32[2]; float* h1f32[2]; half_t* h0f16[2]; half_t* h1f16[2];
    size_t off = 0;
    h0f32[0] = ws + off; off += N1;
    h1f32[1] = ws + off; off += N1;
    h0f16[0] = (half_t*)(ws + off); off += NHalf;
    h1f16[1] = (half_t*)(ws + off); off += NHalf;
    float* lvarr = ws + off; off += (HOR + 1) * 512;
    const size_t zero_floats = off;

    h0f32[1] = ws + off; off += N1;
    h1f32[0] = ws + off; off += N1;
    h0f16[1] = (half_t*)(ws + off); off += NHalf;
    h1f16[0] = (half_t*)(ws + off); off += NHalf;
    float* hdf32[2]; half_t* hd16[2];
    hdf32[0] = ws + off; off += N1;
    hdf32[1] = ws + off; off += N1;
    hd16[0] = (half_t*)(ws + off); off += NHalf;
    hd16[1] = (half_t*)(ws + off); off += NHalf;
    half_t* BL0  = (half_t*)(ws + off); off += (size_t)16 * 3 * 32 * 64 * 8 / 2;
    half_t* BL1  = (half_t*)(ws + off); off += (size_t)16 * 3 * 64 * 64 * 8 / 2;
    half_t* Bdec = (half_t*)(ws + off); off += (size_t)16 * 3 * 32 * 64 * 8 / 2;
    half_t* Blin = (half_t*)(ws + off); off += (size_t)16 * 1 * 32 * 64 * 8 / 2;

    // --- one-time prep ---
    hipMemsetAsync(ws, 0, zero_floats * sizeof(float), stream);
    hipMemsetAsync(out, 0, (size_t)BB * HOR * sizeof(float), stream);
    prep_w2<<<384, 256, 0, stream>>>(Whh0, Whh0, BL0, 32, 3);
    prep_w2<<<768, 256, 0, stream>>>(Wih1, Whh1, BL1, 64, 3);
    prep_w2<<<384, 256, 0, stream>>>(cWhh, cWhh, Bdec, 32, 3);
    prep_w2<<<128, 256, 0, stream>>>(dec0W, dec0W, Blin, 32, 1);
    lv_init_kernel<<<1, 512, 0, stream>>>(src, fcb, lvarr);

    // --- encoder supersteps: L0 at t=s (s<=335), L1 at t=s-1 (s>=1) ---
    for (int s = 0; s <= TT; ++s) {
        const int doL0 = (s <= TT - 1), doL1 = (s >= 1);
        const int nz = doL0 + doL1;
        const int lsel = doL0 ? 0 : 1;
        enc_step<<<dim3(16, 8, nz), 128, 0, stream>>>(
            h0f16[s & 1], h1f16[s & 1], BL0, BL1,
            h0f32[s & 1], h1f32[s & 1],
            h0f32[(s + 1) & 1], h0f16[(s + 1) & 1],
            h1f32[(s + 1) & 1], h1f16[(s + 1) & 1],
            bih0, bhh0, bih1, bhh1, Wih0, src, s, lsel);
    }
    // final h1 = h1(335) in slot 1

    lin_step<<<dim3(16, 8, 1), 128, 0, stream>>>(h1f16[1], Blin, dec0b, hdf32[0], hd16[0]);

    for (int s = 0; s < HOR; ++s) {
        dec_step<<<dim3(16, 8, 1), 128, 0, stream>>>(
            hd16[s & 1], Bdec, hdf32[s & 1],
            hdf32[(s + 1) & 1], hd16[(s + 1) & 1],
            cWih, cbih, cbhh, tff, fcW, fcb,
            lvarr + (size_t)s * 512, lvarr + (size_t)(s + 1) * 512,
            out, s);
    }
}